// Round 5
// baseline (219.855 us; speedup 1.0000x reference)
//
#include <hip/hip_runtime.h>
#include <stdint.h>
#include <stddef.h>

#define IN_F   1024
#define OUT_F  1024
#define NROWS  16384
#define NTERMS 10
#define KT     (IN_F / 32)   // k-tiles (32 k each) per row: 32

typedef __bf16 bf16x8 __attribute__((ext_vector_type(8)));
typedef float  f32x4  __attribute__((ext_vector_type(4)));
typedef unsigned short u16x8 __attribute__((ext_vector_type(8)));

union V8 { u16x8 u; bf16x8 b; };

__device__ __forceinline__ unsigned short f2bf(float f) {
    unsigned int u = __float_as_uint(f);
    unsigned int r = (u + 0x7FFFu + ((u >> 16) & 1u)) >> 16;
    return (unsigned short)r;
}

// ---------------------------------------------------------------- cast x -> bf16
// Emits xb in MFMA-A-native tiled layout: frag (mtile, ktile) is 1 KiB at
// ((mtile*KT + ktile)*64 + lane)*16B; lane l holds A[m=mtile*16+(l&15)]
// [k=ktile*32+(l>>4)*8 .. +8). GEMM A-frag loads become lane-contiguous
// global_load_dwordx4 (no LDS round-trip for A).
__global__ __launch_bounds__(256)
void cast_x_kernel(const float* __restrict__ x, unsigned short* __restrict__ xb) {
    int gt    = blockIdx.x * 256 + threadIdx.x;   // frag-lane slot id
    int lane  = gt & 63;
    int ktile = (gt >> 6) & (KT - 1);
    int mtile = gt >> 11;                         // /(64*KT)
    int m = mtile * 16 + (lane & 15);
    int k = ktile * 32 + (lane >> 4) * 8;
    const float* src = x + (size_t)m * IN_F + k;
    float4 a = *(const float4*)src;
    float4 b = *(const float4*)(src + 4);
    u16x8 o;
    o[0] = f2bf(a.x); o[1] = f2bf(a.y); o[2] = f2bf(a.z); o[3] = f2bf(a.w);
    o[4] = f2bf(b.x); o[5] = f2bf(b.y); o[6] = f2bf(b.z); o[7] = f2bf(b.w);
    *(u16x8*)(xb + (size_t)gt * 8) = o;
}

// ------------------------------------------- base W -> bf16 ; mean spline W -> bf16
__global__ __launch_bounds__(256)
void prep_w_kernel(const float* __restrict__ bw, const float* __restrict__ sw,
                   unsigned short* __restrict__ wb, unsigned short* __restrict__ wm) {
    __shared__ float s[256 * NTERMS];
    const int tid = threadIdx.x;
    const size_t base = (size_t)blockIdx.x * 256;
    const float4* src = (const float4*)(sw + base * NTERMS);
#pragma unroll
    for (int it = 0; it < 3; ++it) {
        int j = tid + it * 256;
        if (j < (256 * NTERMS) / 4) ((float4*)s)[j] = src[j];
    }
    __syncthreads();
    float sum = 0.f;
#pragma unroll
    for (int t = 0; t < NTERMS; ++t) sum += s[tid * NTERMS + t];
    size_t i = base + tid;
    wm[i] = f2bf(sum * 0.1f);
    wb[i] = f2bf(bw[i]);
}

// ---------------------------------------------------------------- fused dual GEMM
// out[m][n] = silu( sum_k x[m][k]*Wb[n][k] ) + sum_k x[m][k]*Wm[n][k]
// 2-barrier K-loop, BK=128 (8 iters). B (both matrices) staged to LDS with
// XOR-16 bank swizzle; A loaded direct global->VGPR from MFMA-native xb.
__global__ __launch_bounds__(256, 2)
void kan_gemm(const unsigned short* __restrict__ xb,
              const unsigned short* __restrict__ wbq,
              const unsigned short* __restrict__ wmq,
              float* __restrict__ out) {
    __shared__ __align__(16) unsigned short Bs[2][128 * 128];   // 64 KiB

    const int tid  = threadIdx.x;
    const int lane = tid & 63;
    const int wave = tid >> 6;
    const int wm_  = wave >> 1;      // m half
    const int wn_  = wave & 1;       // n half
    const int rowl = lane & 15;
    const int quad = lane >> 4;

    const int m0 = blockIdx.x * 128;
    const int n0 = blockIdx.y * 128;
    const int mtb = (m0 >> 4) + wm_ * 4;   // first A mtile for this wave

    f32x4 acc[2][4][4];
#pragma unroll
    for (int s = 0; s < 2; ++s)
#pragma unroll
        for (int mt = 0; mt < 4; ++mt)
#pragma unroll
            for (int nt = 0; nt < 4; ++nt)
                acc[s][mt][nt] = (f32x4){0.f, 0.f, 0.f, 0.f};

    // B staging: 2048 chunks (16 B) per 128x128 tile, 8 per thread per tile.
    // Chunk c of row r lands at slot c ^ (r&15) (self-inverse swizzle).
    int srow[8], sgc[8];
#pragma unroll
    for (int j = 0; j < 8; ++j) {
        int q = tid + j * 256;
        srow[j] = q >> 4;
        sgc[j]  = (q & 15) ^ (srow[j] & 15);
    }

    for (int it = 0; it < 8; ++it) {
        const int k0 = it * 128;
        __syncthreads();
#pragma unroll
        for (int j = 0; j < 8; ++j) {
            int q = tid + j * 256;
            const unsigned short* gb = wbq + (size_t)(n0 + srow[j]) * IN_F + k0 + sgc[j] * 8;
            __builtin_amdgcn_global_load_lds(
                (const __attribute__((address_space(1))) unsigned int*)gb,
                (__attribute__((address_space(3))) unsigned int*)(Bs[0] + q * 8), 16, 0, 0);
            const unsigned short* gm = wmq + (size_t)(n0 + srow[j]) * IN_F + k0 + sgc[j] * 8;
            __builtin_amdgcn_global_load_lds(
                (const __attribute__((address_space(1))) unsigned int*)gm,
                (__attribute__((address_space(3))) unsigned int*)(Bs[1] + q * 8), 16, 0, 0);
        }
        __syncthreads();

        // A frags for ksub=0 (direct from global, MFMA-native)
        bf16x8 afr[2][4];
#pragma unroll
        for (int mt = 0; mt < 4; ++mt) {
            union V8 t;
            t.u = *(const u16x8*)(xb + ((size_t)(mtb + mt) * KT + it * 4) * 512 + lane * 8);
            afr[0][mt] = t.b;
        }

#pragma unroll
        for (int ksub = 0; ksub < 4; ++ksub) {
            if (ksub < 3) {
#pragma unroll
                for (int mt = 0; mt < 4; ++mt) {
                    union V8 t;
                    t.u = *(const u16x8*)(xb + ((size_t)(mtb + mt) * KT + it * 4 + ksub + 1) * 512 + lane * 8);
                    afr[(ksub + 1) & 1][mt] = t.b;
                }
            }
            bf16x8 bfr[2][4];
#pragma unroll
            for (int s = 0; s < 2; ++s)
#pragma unroll
                for (int nt = 0; nt < 4; ++nt) {
                    int r = wn_ * 64 + nt * 16 + rowl;
                    int c = (ksub * 4 + quad) ^ (r & 15);
                    union V8 t;
                    t.u = *(const u16x8*)(Bs[s] + r * 128 + c * 8);
                    bfr[s][nt] = t.b;
                }
#pragma unroll
            for (int s = 0; s < 2; ++s)
#pragma unroll
                for (int mt = 0; mt < 4; ++mt)
#pragma unroll
                    for (int nt = 0; nt < 4; ++nt)
                        acc[s][mt][nt] = __builtin_amdgcn_mfma_f32_16x16x32_bf16(
                            afr[ksub & 1][mt], bfr[s][nt], acc[s][mt][nt], 0, 0, 0);
        }
    }

    // epilogue: silu(base) + spline, fp32 store
    // C/D layout (16x16x32): col = lane&15, row = quad*4 + reg
#pragma unroll
    for (int mt = 0; mt < 4; ++mt)
#pragma unroll
        for (int nt = 0; nt < 4; ++nt)
#pragma unroll
            for (int r = 0; r < 4; ++r) {
                float vb = acc[0][mt][nt][r];
                float vm = acc[1][mt][nt][r];
                float o  = vb / (1.0f + __expf(-vb)) + vm;
                int row = m0 + wm_ * 64 + mt * 16 + quad * 4 + r;
                int col = n0 + wn_ * 64 + nt * 16 + rowl;
                out[(size_t)row * OUT_F + col] = o;
            }
}

extern "C" void kernel_launch(void* const* d_in, const int* in_sizes, int n_in,
                              void* d_out, int out_size, void* d_ws, size_t ws_size,
                              hipStream_t stream) {
    const float* x  = (const float*)d_in[0];   // [16384,1024]
    const float* bw = (const float*)d_in[1];   // [1024,1024]
    const float* sw = (const float*)d_in[2];   // [1024,1024,10]
    float* out = (float*)d_out;                // [16384,1024]

    unsigned short* xb  = (unsigned short*)d_ws;
    unsigned short* wbq = xb + (size_t)NROWS * IN_F;
    unsigned short* wmq = wbq + (size_t)OUT_F * IN_F;

    cast_x_kernel<<<dim3((NROWS * IN_F) / (256 * 8)), dim3(256), 0, stream>>>(x, xb);
    prep_w_kernel<<<dim3((OUT_F * IN_F) / 256), dim3(256), 0, stream>>>(bw, sw, wbq, wmq);
    kan_gemm<<<dim3(NROWS / 128, OUT_F / 128), dim3(256), 0, stream>>>(xb, wbq, wmq, out);
}